// Round 6
// baseline (1285.840 us; speedup 1.0000x reference)
//
#include <hip/hip_runtime.h>
#include <hip/hip_bf16.h>
#include <hip/hip_fp16.h>

// T=5, B=4, M=4096, N=16384, C=128, G=1024, H=4, K=16. fp32 in/out.

typedef __bf16 v8bf __attribute__((ext_vector_type(8)));
typedef float  v4f  __attribute__((ext_vector_type(4)));

__device__ __forceinline__ float lrelu(float x) { return fmaxf(x, 0.2f * x); }

__device__ __forceinline__ unsigned short f2bf(float x) {
  __hip_bfloat16 h = __float2bfloat16(x);
  return __builtin_bit_cast(unsigned short, h);
}
__device__ __forceinline__ float bf2f(unsigned short u) {
  unsigned int t = ((unsigned int)u) << 16;
  return __builtin_bit_cast(float, t);
}

#define GLOAD_LDS16(gp, lp)                                                   \
  __builtin_amdgcn_global_load_lds(                                           \
      (const __attribute__((address_space(1))) void*)(gp),                    \
      (__attribute__((address_space(3))) void*)(lp), 16, 0, 0)

// ---------------------------------------------------------------------------
// Unified NT bf16 MFMA GEMM: A [M x K] row-major, B [N x K] row-major, both
// K-contiguous bf16. 128x128 tile, block 256 (4 waves, each 64x64 via 4x4
// mfma_f32_16x16x32_bf16), BK=32, global_load_lds width-16 staging.
// EP 0: dist:  out f32[row*ldc+col] = 2*acc - aux[col_global]
// EP 1: mlp1:  out bf16 = lrelu(acc + aux[col]); ldc
// EP 2: mlp2:  column mean over 128-row tile of lrelu(acc+aux[col]) ->
//              atomicAdd(outv + (m0>>12)*1024 + col)
// EP 3: xl/xr: out half = acc; ldc
// ---------------------------------------------------------------------------
template<int EP>
__global__ __launch_bounds__(256, 2)
void nt_mfma(const unsigned short* __restrict__ A, const unsigned short* __restrict__ B,
             const float* __restrict__ aux, void* __restrict__ outv, int K, int ldc)
{
  __shared__ __align__(16) unsigned short smem[8192];
  unsigned short* As = smem;
  unsigned short* Bs = smem + 4096;
  const int tid = threadIdx.x;
  const int l = tid & 63;
  const int w = tid >> 6;
  const int wm = w & 1, wn = w >> 1;
  const int m0 = blockIdx.y << 7, n0 = blockIdx.x << 7;
  const int fr = l & 15, quad = l >> 4;
  const int kt = K >> 5;

  const int r0 = tid >> 2, s0 = tid & 3;
  const unsigned short* Aa = A + (size_t)(m0 + r0) * K + s0 * 8;
  const unsigned short* Ab = A + (size_t)(m0 + r0 + 64) * K + s0 * 8;
  const unsigned short* Ba = B + (size_t)(n0 + r0) * K + s0 * 8;
  const unsigned short* Bb = B + (size_t)(n0 + r0 + 64) * K + s0 * 8;
  unsigned short* Ap0 = As + tid * 8;
  unsigned short* Ap1 = As + (tid + 256) * 8;
  unsigned short* Bp0 = Bs + tid * 8;
  unsigned short* Bp1 = Bs + (tid + 256) * 8;

  v4f acc[4][4];
#pragma unroll
  for (int i = 0; i < 4; ++i)
#pragma unroll
    for (int j = 0; j < 4; ++j) acc[i][j] = (v4f){0.f, 0.f, 0.f, 0.f};

  for (int ks = 0; ks < kt; ++ks) {
    GLOAD_LDS16(Aa + ks * 32, Ap0);
    GLOAD_LDS16(Ab + ks * 32, Ap1);
    GLOAD_LDS16(Ba + ks * 32, Bp0);
    GLOAD_LDS16(Bb + ks * 32, Bp1);
    __syncthreads();
    v8bf af[4], bf[4];
#pragma unroll
    for (int i = 0; i < 4; ++i)
      af[i] = *(const v8bf*)(As + (wm * 64 + i * 16 + fr) * 32 + quad * 8);
#pragma unroll
    for (int j = 0; j < 4; ++j)
      bf[j] = *(const v8bf*)(Bs + (wn * 64 + j * 16 + fr) * 32 + quad * 8);
#pragma unroll
    for (int i = 0; i < 4; ++i)
#pragma unroll
      for (int j = 0; j < 4; ++j)
        acc[i][j] = __builtin_amdgcn_mfma_f32_16x16x32_bf16(af[i], bf[j], acc[i][j], 0, 0, 0);
    __syncthreads();
  }

  if (EP == 0) {
    float* S = (float*)outv;
#pragma unroll
    for (int j = 0; j < 4; ++j) {
      int col = n0 + wn * 64 + j * 16 + fr;
      float xs = aux[col];
#pragma unroll
      for (int i = 0; i < 4; ++i) {
        int row = m0 + wm * 64 + i * 16 + quad * 4;
#pragma unroll
        for (int r = 0; r < 4; ++r)
          S[(size_t)(row + r) * ldc + col] = 2.f * acc[i][j][r] - xs;
      }
    }
  } else if (EP == 1) {
    unsigned short* O = (unsigned short*)outv;
#pragma unroll
    for (int j = 0; j < 4; ++j) {
      int col = n0 + wn * 64 + j * 16 + fr;
      float bias = aux[col];
#pragma unroll
      for (int i = 0; i < 4; ++i) {
        int row = m0 + wm * 64 + i * 16 + quad * 4;
#pragma unroll
        for (int r = 0; r < 4; ++r)
          O[(size_t)(row + r) * ldc + col] = f2bf(lrelu(acc[i][j][r] + bias));
      }
    }
  } else if (EP == 2) {
    __syncthreads();
    float* red = (float*)smem;
#pragma unroll
    for (int j = 0; j < 4; ++j) {
      int lcol = wn * 64 + j * 16 + fr;
      float bias = aux[n0 + lcol];
      float s = 0.f;
#pragma unroll
      for (int i = 0; i < 4; ++i)
#pragma unroll
        for (int r = 0; r < 4; ++r) s += lrelu(acc[i][j][r] + bias);
      s += __shfl_xor(s, 16);
      s += __shfl_xor(s, 32);
      if (quad == 0) red[w * 128 + lcol] = s;
    }
    __syncthreads();
    if (tid < 128) {
      float s = (tid < 64) ? red[0 * 128 + tid] + red[1 * 128 + tid]
                           : red[2 * 128 + tid] + red[3 * 128 + tid];
      atomicAdd((float*)outv + ((m0 >> 12) << 10) + n0 + tid, s * (1.0f / 4096.0f));
    }
  } else {  // EP == 3: half store
    __half* O = (__half*)outv;
#pragma unroll
    for (int j = 0; j < 4; ++j) {
      int col = n0 + wn * 64 + j * 16 + fr;
#pragma unroll
      for (int i = 0; i < 4; ++i) {
        int row = m0 + wm * 64 + i * 16 + quad * 4;
#pragma unroll
        for (int r = 0; r < 4; ++r)
          O[(size_t)(row + r) * ldc + col] = __float2half(acc[i][j][r]);
      }
    }
  }
}

// ---------------------------------------------------------------------------
// convert_inputs: seq fp32 -> seqbf (packed hi bf16, all 5 frames), split
// layouts ylay [hi|hi|lo] (frame 4) / xlay [hi|lo|hi] (frames 0..3), and
// xsq = per-row |x|^2 for frames 0..3. 32 threads per row, 8 rows/block.
// ---------------------------------------------------------------------------
__global__ __launch_bounds__(256)
void convert_inputs(const float* __restrict__ seq, unsigned short* __restrict__ seqbf,
                    unsigned short* __restrict__ ylay, unsigned short* __restrict__ xlay,
                    float* __restrict__ xsq)
{
  const int tid = threadIdx.x;
  const int row = blockIdx.x * 8 + (tid >> 5);
  const int c4 = tid & 31;
  float4 v = *(const float4*)(seq + (size_t)row * 128 + c4 * 4);
  ushort4 hi, lo;
  hi.x = f2bf(v.x); lo.x = f2bf(v.x - bf2f(hi.x));
  hi.y = f2bf(v.y); lo.y = f2bf(v.y - bf2f(hi.y));
  hi.z = f2bf(v.z); lo.z = f2bf(v.z - bf2f(hi.z));
  hi.w = f2bf(v.w); lo.w = f2bf(v.w - bf2f(hi.w));
  *(ushort4*)(seqbf + (size_t)row * 128 + c4 * 4) = hi;
  float ss = v.x * v.x + v.y * v.y + v.z * v.z + v.w * v.w;
#pragma unroll
  for (int off = 16; off; off >>= 1) ss += __shfl_xor(ss, off);
  if (row < 65536) {
    unsigned short* p = xlay + (size_t)row * 384 + c4 * 4;
    *(ushort4*)(p) = hi; *(ushort4*)(p + 128) = lo; *(ushort4*)(p + 256) = hi;
    if (c4 == 0) xsq[row] = ss;
  } else {
    unsigned short* p = ylay + (size_t)(row - 65536) * 384 + c4 * 4;
    *(ushort4*)(p) = hi; *(ushort4*)(p + 128) = hi; *(ushort4*)(p + 256) = lo;
  }
}

// ---------------------------------------------------------------------------
// convert_weights: transpose to [N][K] bf16: W1t[128][128], W2t[1024][128],
// split-transpose Wlv[512][384] (segs hi|lo|hi, pairs ylay) and
// Wrv[512][384] (segs hi|hi|lo, pairs xlay); awh = att_w as half.
// ---------------------------------------------------------------------------
__global__ __launch_bounds__(256)
void convert_weights(const float* __restrict__ W1, const float* __restrict__ W2,
                     const float* __restrict__ Wl, const float* __restrict__ Wr,
                     const float* __restrict__ aw,
                     unsigned short* __restrict__ W1t, unsigned short* __restrict__ W2t,
                     unsigned short* __restrict__ Wlv, unsigned short* __restrict__ Wrv,
                     __half* __restrict__ awh)
{
  int idx = blockIdx.x * 256 + threadIdx.x;
  if (idx < 16384) {
    int n = idx >> 7, k = idx & 127;
    W1t[idx] = f2bf(W1[k * 128 + n]);
  } else if (idx < 147456) {
    int i = idx - 16384; int n = i >> 7, k = i & 127;
    W2t[i] = f2bf(W2[k * 1024 + n]);
  } else if (idx < 344064) {
    int i = idx - 147456; int n = i / 384, k = i % 384;
    int s = k >> 7, kk = k & 127;
    float wv = Wl[kk * 512 + n];
    unsigned short h = f2bf(wv);
    Wlv[i] = (s == 1) ? f2bf(wv - bf2f(h)) : h;
  } else if (idx < 540672) {
    int i = idx - 344064; int n = i / 384, k = i % 384;
    int s = k >> 7, kk = k & 127;
    float wv = Wr[kk * 512 + n];
    unsigned short h = f2bf(wv);
    Wrv[i] = (s == 2) ? f2bf(wv - bf2f(h)) : h;
  } else if (idx < 541184) {
    int i = idx - 540672;
    awh[i] = __float2half(aw[i]);
  }
}

// ---------------------------------------------------------------------------
// topk v2 (unchanged): one wave/row; tau = 16th-largest lane-max; compact;
// bitonic top-16 (order irrelevant downstream).
// ---------------------------------------------------------------------------
__global__ __launch_bounds__(256)
void topk2(const float* __restrict__ S, int* __restrict__ nbrOut, int base)
{
  __shared__ float cv[4][256];
  __shared__ int   ci[4][256];
  const int w = threadIdx.x >> 6;
  const int l = threadIdx.x & 63;
  const int row = blockIdx.x * 4 + w;
  const float* Sr = S + (size_t)row * 4096;

  float4 q[16];
#pragma unroll
  for (int c = 0; c < 16; ++c) q[c] = *(const float4*)(Sr + c * 256 + l * 4);

  float m = -3.0e38f;
#pragma unroll
  for (int c = 0; c < 16; ++c)
    m = fmaxf(m, fmaxf(fmaxf(q[c].x, q[c].y), fmaxf(q[c].z, q[c].w)));

#pragma unroll
  for (int k = 2; k <= 64; k <<= 1)
#pragma unroll
    for (int j = k >> 1; j > 0; j >>= 1) {
      float o = __shfl_xor(m, j);
      bool takeMax = (((l & k) == 0) == ((l & j) != 0));
      bool take = (takeMax == (o > m));
      m = take ? o : m;
    }
  float tau = __shfl(m, 48);

  int cnt = 0;
#pragma unroll
  for (int c = 0; c < 16; ++c) {
    float vv[4] = {q[c].x, q[c].y, q[c].z, q[c].w};
#pragma unroll
    for (int e = 0; e < 4; ++e) {
      bool p = vv[e] >= tau;
      unsigned long long mask = __ballot(p);
      if (p) {
        int pos = cnt + __popcll(mask & ((1ull << l) - 1ull));
        if (pos < 256) { cv[w][pos] = vv[e]; ci[w][pos] = c * 256 + l * 4 + e; }
      }
      cnt += __popcll(mask);
    }
  }
  __syncthreads();
  int ccnt = cnt < 256 ? cnt : 256;

  if (ccnt <= 64) {
    float bv = (l < ccnt) ? cv[w][l] : -3.0e38f;
    int   bi = (l < ccnt) ? ci[w][l] : -1;
#pragma unroll
    for (int k = 2; k <= 64; k <<= 1)
#pragma unroll
      for (int j = k >> 1; j > 0; j >>= 1) {
        float ov = __shfl_xor(bv, j);
        int   oi = __shfl_xor(bi, j);
        bool takeMax = (((l & k) == 0) == ((l & j) != 0));
        bool take = (takeMax == (ov > bv));
        bv = take ? ov : bv;
        bi = take ? oi : bi;
      }
    if (l >= 48) nbrOut[row * 16 + (l - 48)] = base + bi;
  } else {
    float a0 = (l < ccnt) ? cv[w][l] : -3.0e38f;
    float a1 = (l + 64 < ccnt) ? cv[w][l + 64] : -3.0e38f;
    float a2 = (l + 128 < ccnt) ? cv[w][l + 128] : -3.0e38f;
    float a3 = (l + 192 < ccnt) ? cv[w][l + 192] : -3.0e38f;
    int i0 = (l < ccnt) ? ci[w][l] : -1;
    int i1 = (l + 64 < ccnt) ? ci[w][l + 64] : -2;
    int i2 = (l + 128 < ccnt) ? ci[w][l + 128] : -3;
    int i3 = (l + 192 < ccnt) ? ci[w][l + 192] : -4;
    for (int sel = 0; sel < 16; ++sel) {
      float best = a0; int bi = i0;
      if (a1 > best) { best = a1; bi = i1; }
      if (a2 > best) { best = a2; bi = i2; }
      if (a3 > best) { best = a3; bi = i3; }
#pragma unroll
      for (int off = 32; off; off >>= 1) {
        float ov = __shfl_xor(best, off);
        int oi = __shfl_xor(bi, off);
        if (ov > best) { best = ov; bi = oi; }
      }
      if (i0 == bi) a0 = -3.0e38f;
      if (i1 == bi) a1 = -3.0e38f;
      if (i2 == bi) a2 = -3.0e38f;
      if (i3 == bi) a3 = -3.0e38f;
      if (l == sel) nbrOut[row * 16 + sel] = base + bi;
    }
  }
}

// ---------------------------------------------------------------------------
// Temporal attention weights (unchanged)
// ---------------------------------------------------------------------------
__global__ __launch_bounds__(1024)
void temporal_attn(const float* __restrict__ gfea, float* __restrict__ attnw)
{
  const int tid = threadIdx.x;
  const int w = tid >> 6, l = tid & 63;
  const int b = w >> 2, i = w & 3;
  const float* q  = gfea + (16 + b) * 1024;
  const float* kv = gfea + (i * 4 + b) * 1024;
  float p = 0.f;
  for (int g = l; g < 1024; g += 64) p += q[g] * kv[g];
#pragma unroll
  for (int off = 32; off; off >>= 1) p += __shfl_xor(p, off);
  __shared__ float sc[16];
  if (l == 0) sc[w] = p * 0.03125f;
  __syncthreads();
  if (tid < 4) {
    float v0 = sc[tid * 4 + 0], v1 = sc[tid * 4 + 1];
    float v2 = sc[tid * 4 + 2], v3 = sc[tid * 4 + 3];
    float mm = fmaxf(fmaxf(v0, v1), fmaxf(v2, v3));
    v0 = __expf(v0 - mm); v1 = __expf(v1 - mm);
    v2 = __expf(v2 - mm); v3 = __expf(v3 - mm);
    float inv = 1.f / (v0 + v1 + v2 + v3);
    attnw[tid * 4 + 0] = v0 * inv;
    attnw[tid * 4 + 1] = v1 * inv;
    attnw[tid * 4 + 2] = v2 * inv;
    attnw[tid * 4 + 3] = v3 * inv;
  }
}

// ---------------------------------------------------------------------------
// gat5: register-held single-fetch GATv2. One wave per (query, frame);
// lane = (head h = l>>4, cg = l&15), 8 channels/lane. All 16 neighbor rows
// gathered ONCE up-front into 64 VGPRs (independent dwordx4 loads -> deep
// MLP); e-pass and aggregate-pass both read registers. No LDS, no barriers,
// no loop-carried exp chain (vs gat4), no second gather (vs gat3).
// ---------------------------------------------------------------------------
__global__ __launch_bounds__(256, 4)
void gat5(const __half* __restrict__ xlh, const __half* __restrict__ xrh,
          const int* __restrict__ nbr, const __half* __restrict__ awh,
          const float* __restrict__ attnw, float* __restrict__ wgt4)
{
  const int tid = threadIdx.x;
  const int l = tid & 63;
  const int qid = blockIdx.x * 4 + (tid >> 6);   // [0, 65536)
  const int f = qid >> 14, n = qid & 16383, b = n >> 12;
  const int h = l >> 4, cp = l & 15;
  const float fw = attnw[b * 4 + f] * 0.25f;

  const int jl = nbr[qid * 16 + (l & 15)];

  // gather all 16 neighbor rows, 16 B/lane, held as packed half in regs
  float4 xv[16];
#pragma unroll
  for (int k = 0; k < 16; ++k) {
    int j = __shfl(jl, k);
    xv[k] = *(const float4*)(xlh + (size_t)j * 512 + h * 128 + cp * 8);
  }

  const __half2* xrp = (const __half2*)(xrh + (size_t)qid * 512 + h * 128 + cp * 8);
  float2 xr0 = __half22float2(xrp[0]), xr1 = __half22float2(xrp[1]);
  float2 xr2 = __half22float2(xrp[2]), xr3 = __half22float2(xrp[3]);
  const __half2* awp = (const __half2*)(awh + h * 128 + cp * 8);
  float2 aw0 = __half22float2(awp[0]), aw1 = __half22float2(awp[1]);
  float2 aw2 = __half22float2(awp[2]), aw3 = __half22float2(awp[3]);

  float e[16];
#pragma unroll
  for (int k = 0; k < 16; ++k) {
    const __half2* hp = (const __half2*)&xv[k];
    float2 x0 = __half22float2(hp[0]), x1 = __half22float2(hp[1]);
    float2 x2 = __half22float2(hp[2]), x3 = __half22float2(hp[3]);
    float p = 0.f;
    p += lrelu(x0.x + xr0.x) * aw0.x + lrelu(x0.y + xr0.y) * aw0.y;
    p += lrelu(x1.x + xr1.x) * aw1.x + lrelu(x1.y + xr1.y) * aw1.y;
    p += lrelu(x2.x + xr2.x) * aw2.x + lrelu(x2.y + xr2.y) * aw2.y;
    p += lrelu(x3.x + xr3.x) * aw3.x + lrelu(x3.y + xr3.y) * aw3.y;
    p += __shfl_xor(p, 1);
    p += __shfl_xor(p, 2);
    p += __shfl_xor(p, 4);
    p += __shfl_xor(p, 8);
    e[k] = p;
  }

  float m = e[0];
#pragma unroll
  for (int k = 1; k < 16; ++k) m = fmaxf(m, e[k]);
  float s = 0.f;
#pragma unroll
  for (int k = 0; k < 16; ++k) { e[k] = __expf(e[k] - m); s += e[k]; }
  const float sc = fw / s;

  float o[8];
#pragma unroll
  for (int c = 0; c < 8; ++c) o[c] = 0.f;
#pragma unroll
  for (int k = 0; k < 16; ++k) {
    const __half2* hp = (const __half2*)&xv[k];
    float ak = e[k] * sc;
    float2 f0 = __half22float2(hp[0]);
    float2 f1 = __half22float2(hp[1]);
    float2 f2 = __half22float2(hp[2]);
    float2 f3 = __half22float2(hp[3]);
    o[0] += ak * f0.x; o[1] += ak * f0.y;
    o[2] += ak * f1.x; o[3] += ak * f1.y;
    o[4] += ak * f2.x; o[5] += ak * f2.y;
    o[6] += ak * f3.x; o[7] += ak * f3.y;
  }
#pragma unroll
  for (int c = 0; c < 8; ++c) {
    float t = o[c];
    t += __shfl_xor(t, 16);
    t += __shfl_xor(t, 32);
    o[c] = t;
  }
  if (l < 16) {
    float* wp = wgt4 + (size_t)qid * 128 + l * 8;
    *(float4*)(wp)     = make_float4(o[0], o[1], o[2], o[3]);
    *(float4*)(wp + 4) = make_float4(o[4], o[5], o[6], o[7]);
  }
}

// ---------------------------------------------------------------------------
// finalize: out[n,0:128]=last[n]; out[n,128:256]=sum_f wgt4[f][n]
// ---------------------------------------------------------------------------
__global__ __launch_bounds__(256)
void finalize2(const float* __restrict__ last, const float* __restrict__ wgt4,
               float* __restrict__ out)
{
  int idx = blockIdx.x * 256 + threadIdx.x;
  int n = idx >> 6, q = idx & 63;
  float4 v;
  if (q < 32) {
    v = *(const float4*)(last + (size_t)n * 128 + 4 * q);
  } else {
    int c = (q - 32) * 4;
    v = make_float4(0.f, 0.f, 0.f, 0.f);
#pragma unroll
    for (int f = 0; f < 4; ++f) {
      float4 t = *(const float4*)(wgt4 + ((size_t)f * 16384 + n) * 128 + c);
      v.x += t.x; v.y += t.y; v.z += t.z; v.w += t.w;
    }
  }
  *(float4*)(out + (size_t)n * 256 + 4 * q) = v;
}

extern "C" void kernel_launch(void* const* d_in, const int* in_sizes, int n_in,
                              void* d_out, int out_size, void* d_ws, size_t ws_size,
                              hipStream_t stream)
{
  (void)in_sizes; (void)n_in; (void)out_size; (void)ws_size;
  const float* seq = (const float*)d_in[0];
  const float* W1  = (const float*)d_in[1];
  const float* b1  = (const float*)d_in[2];
  const float* W2  = (const float*)d_in[3];
  const float* b2  = (const float*)d_in[4];
  const float* Wl  = (const float*)d_in[5];
  const float* Wr  = (const float*)d_in[6];
  const float* aw  = (const float*)d_in[7];
  float* out = (float*)d_out;

  // workspace layout (float offsets); ~178 MiB total
  float* ws = (float*)d_ws;
  float* S             = ws;                                   // 16,777,216 f (dist phase)
  __half* xrh          = (__half*)ws;                          // alias: 65536x512 half (after dist)
  unsigned short* seqbf = (unsigned short*)(ws + 16777216);    // 10,485,760 us
  unsigned short* h1bf  = (unsigned short*)(ws + 22020096);    // 10,485,760 us
  __half* xlh           = (__half*)(ws + 22020096);            // alias after mlp2: 16384x512 half
  unsigned short* ylay  = (unsigned short*)(ws + 27262976);    // 6,291,456 us
  unsigned short* xlay  = (unsigned short*)(ws + 30408704);    // 25,165,824 us
  float* wgt4           = ws + 30408704;                       // alias after xr gemm: 8,388,608 f
  float* gfea           = ws + 42991616;                       // 20,480
  float* attn           = gfea + 20480;                        // 16
  float* xsq            = attn + 16;                           // 65,536
  int*   nbr            = (int*)(xsq + 65536);                 // 1,048,576 ints
  unsigned short* W1t   = (unsigned short*)(nbr + 1048576);    // 16,384 us
  unsigned short* W2t   = W1t + 16384;                         // 131,072 us
  unsigned short* Wlv   = W2t + 131072;                        // 196,608 us
  unsigned short* Wrv   = Wlv + 196608;                        // 196,608 us
  __half* awh           = (__half*)(Wrv + 196608);             // 512 halves

  (void)hipMemsetAsync(gfea, 0, 20480 * sizeof(float), stream);

  // conversions
  convert_inputs<<<10240, 256, 0, stream>>>(seq, seqbf, ylay, xlay, xsq);
  convert_weights<<<2114, 256, 0, stream>>>(W1, W2, Wl, Wr, aw, W1t, W2t, Wlv, Wrv, awh);

  // MLP (bf16 MFMA) + temporal attention
  nt_mfma<1><<<dim3(1, 640), 256, 0, stream>>>(seqbf, W1t, b1, h1bf, 128, 128);
  nt_mfma<2><<<dim3(8, 640), 256, 0, stream>>>(h1bf, W2t, b2, gfea, 128, 0);
  temporal_attn<<<1, 1024, 0, stream>>>(gfea, attn);

  // KNN: 16x (split-bf16 dist MFMA + topk)
  for (int f = 0; f < 4; ++f)
    for (int b = 0; b < 4; ++b) {
      nt_mfma<0><<<dim3(32, 32), 256, 0, stream>>>(
          ylay + (size_t)b * 4096 * 384,
          xlay + ((size_t)f * 16384 + (size_t)b * 4096) * 384,
          xsq + f * 16384 + b * 4096, S, 384, 4096);
      topk2<<<1024, 256, 0, stream>>>(S, nbr + (f * 16384 + b * 4096) * 16, b * 4096);
    }

  // GAT projections (split-bf16 MFMA -> half) — xrh aliases S (dist done)
  nt_mfma<3><<<dim3(4, 128), 256, 0, stream>>>(ylay, Wlv, nullptr, xlh, 384, 512);
  nt_mfma<3><<<dim3(4, 512), 256, 0, stream>>>(xlay, Wrv, nullptr, xrh, 384, 512);

  // GAT gather/softmax/aggregate, all 4 frames, single fetch per neighbor
  gat5<<<16384, 256, 0, stream>>>(xlh, xrh, nbr, awh, attn, wgt4);

  finalize2<<<4096, 256, 0, stream>>>(seq + (size_t)4 * 16384 * 128, wgt4, out);
}

// Round 7
// 1021.317 us; speedup vs baseline: 1.2590x; 1.2590x over previous
//
#include <hip/hip_runtime.h>
#include <hip/hip_bf16.h>
#include <hip/hip_fp16.h>

// T=5, B=4, M=4096, N=16384, C=128, G=1024, H=4, K=16. fp32 in/out.

typedef __bf16 v8bf __attribute__((ext_vector_type(8)));
typedef float  v4f  __attribute__((ext_vector_type(4)));

__device__ __forceinline__ float lrelu(float x) { return fmaxf(x, 0.2f * x); }

__device__ __forceinline__ unsigned short f2bf(float x) {
  __hip_bfloat16 h = __float2bfloat16(x);
  return __builtin_bit_cast(unsigned short, h);
}
__device__ __forceinline__ float bf2f(unsigned short u) {
  unsigned int t = ((unsigned int)u) << 16;
  return __builtin_bit_cast(float, t);
}

#define GLOAD_LDS16(gp, lp)                                                   \
  __builtin_amdgcn_global_load_lds(                                           \
      (const __attribute__((address_space(1))) void*)(gp),                    \
      (__attribute__((address_space(3))) void*)(lp), 16, 0, 0)

// ---------------------------------------------------------------------------
// Unified NT bf16 MFMA GEMM: A [M x K] row-major, B [N x K] row-major, both
// K-contiguous bf16. 128x128 tile, block 256 (4 waves, each 64x64 via 4x4
// mfma_f32_16x16x32_bf16), BK=32, global_load_lds width-16 staging.
// EP 0: dist:  out f32[row*ldc+col] = 2*acc - aux[col_global]
// EP 1: mlp1:  out bf16 = lrelu(acc + aux[col]); ldc
// EP 2: mlp2:  column mean over 128-row tile of lrelu(acc+aux[col]) ->
//              atomicAdd(outv + (m0>>12)*1024 + col)
// EP 3: xl/xr: out half = acc; ldc
// ---------------------------------------------------------------------------
template<int EP>
__global__ __launch_bounds__(256, 2)
void nt_mfma(const unsigned short* __restrict__ A, const unsigned short* __restrict__ B,
             const float* __restrict__ aux, void* __restrict__ outv, int K, int ldc)
{
  __shared__ __align__(16) unsigned short smem[8192];
  unsigned short* As = smem;
  unsigned short* Bs = smem + 4096;
  const int tid = threadIdx.x;
  const int l = tid & 63;
  const int w = tid >> 6;
  const int wm = w & 1, wn = w >> 1;
  const int m0 = blockIdx.y << 7, n0 = blockIdx.x << 7;
  const int fr = l & 15, quad = l >> 4;
  const int kt = K >> 5;

  const int r0 = tid >> 2, s0 = tid & 3;
  const unsigned short* Aa = A + (size_t)(m0 + r0) * K + s0 * 8;
  const unsigned short* Ab = A + (size_t)(m0 + r0 + 64) * K + s0 * 8;
  const unsigned short* Ba = B + (size_t)(n0 + r0) * K + s0 * 8;
  const unsigned short* Bb = B + (size_t)(n0 + r0 + 64) * K + s0 * 8;
  unsigned short* Ap0 = As + tid * 8;
  unsigned short* Ap1 = As + (tid + 256) * 8;
  unsigned short* Bp0 = Bs + tid * 8;
  unsigned short* Bp1 = Bs + (tid + 256) * 8;

  v4f acc[4][4];
#pragma unroll
  for (int i = 0; i < 4; ++i)
#pragma unroll
    for (int j = 0; j < 4; ++j) acc[i][j] = (v4f){0.f, 0.f, 0.f, 0.f};

  for (int ks = 0; ks < kt; ++ks) {
    GLOAD_LDS16(Aa + ks * 32, Ap0);
    GLOAD_LDS16(Ab + ks * 32, Ap1);
    GLOAD_LDS16(Ba + ks * 32, Bp0);
    GLOAD_LDS16(Bb + ks * 32, Bp1);
    __syncthreads();
    v8bf af[4], bf[4];
#pragma unroll
    for (int i = 0; i < 4; ++i)
      af[i] = *(const v8bf*)(As + (wm * 64 + i * 16 + fr) * 32 + quad * 8);
#pragma unroll
    for (int j = 0; j < 4; ++j)
      bf[j] = *(const v8bf*)(Bs + (wn * 64 + j * 16 + fr) * 32 + quad * 8);
#pragma unroll
    for (int i = 0; i < 4; ++i)
#pragma unroll
      for (int j = 0; j < 4; ++j)
        acc[i][j] = __builtin_amdgcn_mfma_f32_16x16x32_bf16(af[i], bf[j], acc[i][j], 0, 0, 0);
    __syncthreads();
  }

  if (EP == 0) {
    float* S = (float*)outv;
#pragma unroll
    for (int j = 0; j < 4; ++j) {
      int col = n0 + wn * 64 + j * 16 + fr;
      float xs = aux[col];
#pragma unroll
      for (int i = 0; i < 4; ++i) {
        int row = m0 + wm * 64 + i * 16 + quad * 4;
#pragma unroll
        for (int r = 0; r < 4; ++r)
          S[(size_t)(row + r) * ldc + col] = 2.f * acc[i][j][r] - xs;
      }
    }
  } else if (EP == 1) {
    unsigned short* O = (unsigned short*)outv;
#pragma unroll
    for (int j = 0; j < 4; ++j) {
      int col = n0 + wn * 64 + j * 16 + fr;
      float bias = aux[col];
#pragma unroll
      for (int i = 0; i < 4; ++i) {
        int row = m0 + wm * 64 + i * 16 + quad * 4;
#pragma unroll
        for (int r = 0; r < 4; ++r)
          O[(size_t)(row + r) * ldc + col] = f2bf(lrelu(acc[i][j][r] + bias));
      }
    }
  } else if (EP == 2) {
    __syncthreads();
    float* red = (float*)smem;
#pragma unroll
    for (int j = 0; j < 4; ++j) {
      int lcol = wn * 64 + j * 16 + fr;
      float bias = aux[n0 + lcol];
      float s = 0.f;
#pragma unroll
      for (int i = 0; i < 4; ++i)
#pragma unroll
        for (int r = 0; r < 4; ++r) s += lrelu(acc[i][j][r] + bias);
      s += __shfl_xor(s, 16);
      s += __shfl_xor(s, 32);
      if (quad == 0) red[w * 128 + lcol] = s;
    }
    __syncthreads();
    if (tid < 128) {
      float s = (tid < 64) ? red[0 * 128 + tid] + red[1 * 128 + tid]
                           : red[2 * 128 + tid] + red[3 * 128 + tid];
      atomicAdd((float*)outv + ((m0 >> 12) << 10) + n0 + tid, s * (1.0f / 4096.0f));
    }
  } else {  // EP == 3: half store
    __half* O = (__half*)outv;
#pragma unroll
    for (int j = 0; j < 4; ++j) {
      int col = n0 + wn * 64 + j * 16 + fr;
#pragma unroll
      for (int i = 0; i < 4; ++i) {
        int row = m0 + wm * 64 + i * 16 + quad * 4;
#pragma unroll
        for (int r = 0; r < 4; ++r)
          O[(size_t)(row + r) * ldc + col] = __float2half(acc[i][j][r]);
      }
    }
  }
}

// ---------------------------------------------------------------------------
// convert_inputs: seq fp32 -> seqbf (packed hi bf16, all 5 frames), split
// layouts ylay [hi|hi|lo] (frame 4) / xlay [hi|lo|hi] (frames 0..3), and
// xsq = per-row |x|^2 for frames 0..3. 32 threads per row, 8 rows/block.
// ---------------------------------------------------------------------------
__global__ __launch_bounds__(256)
void convert_inputs(const float* __restrict__ seq, unsigned short* __restrict__ seqbf,
                    unsigned short* __restrict__ ylay, unsigned short* __restrict__ xlay,
                    float* __restrict__ xsq)
{
  const int tid = threadIdx.x;
  const int row = blockIdx.x * 8 + (tid >> 5);
  const int c4 = tid & 31;
  float4 v = *(const float4*)(seq + (size_t)row * 128 + c4 * 4);
  ushort4 hi, lo;
  hi.x = f2bf(v.x); lo.x = f2bf(v.x - bf2f(hi.x));
  hi.y = f2bf(v.y); lo.y = f2bf(v.y - bf2f(hi.y));
  hi.z = f2bf(v.z); lo.z = f2bf(v.z - bf2f(hi.z));
  hi.w = f2bf(v.w); lo.w = f2bf(v.w - bf2f(hi.w));
  *(ushort4*)(seqbf + (size_t)row * 128 + c4 * 4) = hi;
  float ss = v.x * v.x + v.y * v.y + v.z * v.z + v.w * v.w;
#pragma unroll
  for (int off = 16; off; off >>= 1) ss += __shfl_xor(ss, off);
  if (row < 65536) {
    unsigned short* p = xlay + (size_t)row * 384 + c4 * 4;
    *(ushort4*)(p) = hi; *(ushort4*)(p + 128) = lo; *(ushort4*)(p + 256) = hi;
    if (c4 == 0) xsq[row] = ss;
  } else {
    unsigned short* p = ylay + (size_t)(row - 65536) * 384 + c4 * 4;
    *(ushort4*)(p) = hi; *(ushort4*)(p + 128) = hi; *(ushort4*)(p + 256) = lo;
  }
}

// ---------------------------------------------------------------------------
// convert_weights: transpose to [N][K] bf16: W1t[128][128], W2t[1024][128],
// split-transpose Wlv[512][384] (segs hi|lo|hi, pairs ylay) and
// Wrv[512][384] (segs hi|hi|lo, pairs xlay); awh = att_w as half.
// ---------------------------------------------------------------------------
__global__ __launch_bounds__(256)
void convert_weights(const float* __restrict__ W1, const float* __restrict__ W2,
                     const float* __restrict__ Wl, const float* __restrict__ Wr,
                     const float* __restrict__ aw,
                     unsigned short* __restrict__ W1t, unsigned short* __restrict__ W2t,
                     unsigned short* __restrict__ Wlv, unsigned short* __restrict__ Wrv,
                     __half* __restrict__ awh)
{
  int idx = blockIdx.x * 256 + threadIdx.x;
  if (idx < 16384) {
    int n = idx >> 7, k = idx & 127;
    W1t[idx] = f2bf(W1[k * 128 + n]);
  } else if (idx < 147456) {
    int i = idx - 16384; int n = i >> 7, k = i & 127;
    W2t[i] = f2bf(W2[k * 1024 + n]);
  } else if (idx < 344064) {
    int i = idx - 147456; int n = i / 384, k = i % 384;
    int s = k >> 7, kk = k & 127;
    float wv = Wl[kk * 512 + n];
    unsigned short h = f2bf(wv);
    Wlv[i] = (s == 1) ? f2bf(wv - bf2f(h)) : h;
  } else if (idx < 540672) {
    int i = idx - 344064; int n = i / 384, k = i % 384;
    int s = k >> 7, kk = k & 127;
    float wv = Wr[kk * 512 + n];
    unsigned short h = f2bf(wv);
    Wrv[i] = (s == 2) ? f2bf(wv - bf2f(h)) : h;
  } else if (idx < 541184) {
    int i = idx - 540672;
    awh[i] = __float2half(aw[i]);
  }
}

// ---------------------------------------------------------------------------
// topk v2 (unchanged): one wave/row; tau = 16th-largest lane-max; compact;
// bitonic top-16 (order irrelevant downstream).
// ---------------------------------------------------------------------------
__global__ __launch_bounds__(256)
void topk2(const float* __restrict__ S, int* __restrict__ nbrOut, int base)
{
  __shared__ float cv[4][256];
  __shared__ int   ci[4][256];
  const int w = threadIdx.x >> 6;
  const int l = threadIdx.x & 63;
  const int row = blockIdx.x * 4 + w;
  const float* Sr = S + (size_t)row * 4096;

  float4 q[16];
#pragma unroll
  for (int c = 0; c < 16; ++c) q[c] = *(const float4*)(Sr + c * 256 + l * 4);

  float m = -3.0e38f;
#pragma unroll
  for (int c = 0; c < 16; ++c)
    m = fmaxf(m, fmaxf(fmaxf(q[c].x, q[c].y), fmaxf(q[c].z, q[c].w)));

#pragma unroll
  for (int k = 2; k <= 64; k <<= 1)
#pragma unroll
    for (int j = k >> 1; j > 0; j >>= 1) {
      float o = __shfl_xor(m, j);
      bool takeMax = (((l & k) == 0) == ((l & j) != 0));
      bool take = (takeMax == (o > m));
      m = take ? o : m;
    }
  float tau = __shfl(m, 48);

  int cnt = 0;
#pragma unroll
  for (int c = 0; c < 16; ++c) {
    float vv[4] = {q[c].x, q[c].y, q[c].z, q[c].w};
#pragma unroll
    for (int e = 0; e < 4; ++e) {
      bool p = vv[e] >= tau;
      unsigned long long mask = __ballot(p);
      if (p) {
        int pos = cnt + __popcll(mask & ((1ull << l) - 1ull));
        if (pos < 256) { cv[w][pos] = vv[e]; ci[w][pos] = c * 256 + l * 4 + e; }
      }
      cnt += __popcll(mask);
    }
  }
  __syncthreads();
  int ccnt = cnt < 256 ? cnt : 256;

  if (ccnt <= 64) {
    float bv = (l < ccnt) ? cv[w][l] : -3.0e38f;
    int   bi = (l < ccnt) ? ci[w][l] : -1;
#pragma unroll
    for (int k = 2; k <= 64; k <<= 1)
#pragma unroll
      for (int j = k >> 1; j > 0; j >>= 1) {
        float ov = __shfl_xor(bv, j);
        int   oi = __shfl_xor(bi, j);
        bool takeMax = (((l & k) == 0) == ((l & j) != 0));
        bool take = (takeMax == (ov > bv));
        bv = take ? ov : bv;
        bi = take ? oi : bi;
      }
    if (l >= 48) nbrOut[row * 16 + (l - 48)] = base + bi;
  } else {
    float a0 = (l < ccnt) ? cv[w][l] : -3.0e38f;
    float a1 = (l + 64 < ccnt) ? cv[w][l + 64] : -3.0e38f;
    float a2 = (l + 128 < ccnt) ? cv[w][l + 128] : -3.0e38f;
    float a3 = (l + 192 < ccnt) ? cv[w][l + 192] : -3.0e38f;
    int i0 = (l < ccnt) ? ci[w][l] : -1;
    int i1 = (l + 64 < ccnt) ? ci[w][l + 64] : -2;
    int i2 = (l + 128 < ccnt) ? ci[w][l + 128] : -3;
    int i3 = (l + 192 < ccnt) ? ci[w][l + 192] : -4;
    for (int sel = 0; sel < 16; ++sel) {
      float best = a0; int bi = i0;
      if (a1 > best) { best = a1; bi = i1; }
      if (a2 > best) { best = a2; bi = i2; }
      if (a3 > best) { best = a3; bi = i3; }
#pragma unroll
      for (int off = 32; off; off >>= 1) {
        float ov = __shfl_xor(best, off);
        int oi = __shfl_xor(bi, off);
        if (ov > best) { best = ov; bi = oi; }
      }
      if (i0 == bi) a0 = -3.0e38f;
      if (i1 == bi) a1 = -3.0e38f;
      if (i2 == bi) a2 = -3.0e38f;
      if (i3 == bi) a3 = -3.0e38f;
      if (l == sel) nbrOut[row * 16 + sel] = base + bi;
    }
  }
}

// ---------------------------------------------------------------------------
// Temporal attention weights (unchanged)
// ---------------------------------------------------------------------------
__global__ __launch_bounds__(1024)
void temporal_attn(const float* __restrict__ gfea, float* __restrict__ attnw)
{
  const int tid = threadIdx.x;
  const int w = tid >> 6, l = tid & 63;
  const int b = w >> 2, i = w & 3;
  const float* q  = gfea + (16 + b) * 1024;
  const float* kv = gfea + (i * 4 + b) * 1024;
  float p = 0.f;
  for (int g = l; g < 1024; g += 64) p += q[g] * kv[g];
#pragma unroll
  for (int off = 32; off; off >>= 1) p += __shfl_xor(p, off);
  __shared__ float sc[16];
  if (l == 0) sc[w] = p * 0.03125f;
  __syncthreads();
  if (tid < 4) {
    float v0 = sc[tid * 4 + 0], v1 = sc[tid * 4 + 1];
    float v2 = sc[tid * 4 + 2], v3 = sc[tid * 4 + 3];
    float mm = fmaxf(fmaxf(v0, v1), fmaxf(v2, v3));
    v0 = __expf(v0 - mm); v1 = __expf(v1 - mm);
    v2 = __expf(v2 - mm); v3 = __expf(v3 - mm);
    float inv = 1.f / (v0 + v1 + v2 + v3);
    attnw[tid * 4 + 0] = v0 * inv;
    attnw[tid * 4 + 1] = v1 * inv;
    attnw[tid * 4 + 2] = v2 * inv;
    attnw[tid * 4 + 3] = v3 * inv;
  }
}

// ---------------------------------------------------------------------------
// gat6: chunked single-fetch GATv2. One wave per (query, frame); lane =
// (head h = l>>4, cg = l&15), 8 channels/lane. Neighbors processed in 2
// chunks of 8: chunk rows held in 32 VGPRs (no spill — gat5's 64-VGPR xv
// spilled ~1 GB to scratch), e's computed independently within the chunk,
// ONE online-softmax merge per chunk (not per neighbor like gat4). Single
// gather per neighbor (vs gat3's two). No LDS, no barriers.
// ---------------------------------------------------------------------------
__global__ __launch_bounds__(256)
void gat6(const __half* __restrict__ xlh, const __half* __restrict__ xrh,
          const int* __restrict__ nbr, const __half* __restrict__ awh,
          const float* __restrict__ attnw, float* __restrict__ wgt4)
{
  const int tid = threadIdx.x;
  const int l = tid & 63;
  const int qid = blockIdx.x * 4 + (tid >> 6);   // [0, 65536)
  const int f = qid >> 14, n = qid & 16383, b = n >> 12;
  const int h = l >> 4, cp = l & 15;
  const float fw = attnw[b * 4 + f] * 0.25f;

  const int jl = nbr[qid * 16 + (l & 15)];
  const __half* xbase = xlh + h * 128 + cp * 8;

  const __half2* xrp = (const __half2*)(xrh + (size_t)qid * 512 + h * 128 + cp * 8);
  float2 xr0 = __half22float2(xrp[0]), xr1 = __half22float2(xrp[1]);
  float2 xr2 = __half22float2(xrp[2]), xr3 = __half22float2(xrp[3]);
  const __half2* awp = (const __half2*)(awh + h * 128 + cp * 8);
  float2 aw0 = __half22float2(awp[0]), aw1 = __half22float2(awp[1]);
  float2 aw2 = __half22float2(awp[2]), aw3 = __half22float2(awp[3]);

  float m = -3.0e38f, s = 0.f;
  float o[8];
#pragma unroll
  for (int c = 0; c < 8; ++c) o[c] = 0.f;

  for (int ch = 0; ch < 2; ++ch) {
    // gather this chunk's 8 neighbor rows (independent dwordx4 loads)
    float4 xv[8];
#pragma unroll
    for (int k = 0; k < 8; ++k) {
      int j = __shfl(jl, ch * 8 + k);
      xv[k] = *(const float4*)(xbase + (size_t)j * 512);
    }
    // e's for the chunk (independent)
    float e[8];
#pragma unroll
    for (int k = 0; k < 8; ++k) {
      const __half2* hp = (const __half2*)&xv[k];
      float2 x0 = __half22float2(hp[0]), x1 = __half22float2(hp[1]);
      float2 x2 = __half22float2(hp[2]), x3 = __half22float2(hp[3]);
      float p = 0.f;
      p += lrelu(x0.x + xr0.x) * aw0.x + lrelu(x0.y + xr0.y) * aw0.y;
      p += lrelu(x1.x + xr1.x) * aw1.x + lrelu(x1.y + xr1.y) * aw1.y;
      p += lrelu(x2.x + xr2.x) * aw2.x + lrelu(x2.y + xr2.y) * aw2.y;
      p += lrelu(x3.x + xr3.x) * aw3.x + lrelu(x3.y + xr3.y) * aw3.y;
      p += __shfl_xor(p, 1);
      p += __shfl_xor(p, 2);
      p += __shfl_xor(p, 4);
      p += __shfl_xor(p, 8);
      e[k] = p;
    }
    // one merge per chunk
    float mc = e[0];
#pragma unroll
    for (int k = 1; k < 8; ++k) mc = fmaxf(mc, e[k]);
    float mn = fmaxf(m, mc);
    float cr = __expf(m - mn);   // first chunk: exp(-huge) = 0
    s *= cr;
#pragma unroll
    for (int c = 0; c < 8; ++c) o[c] *= cr;
#pragma unroll
    for (int k = 0; k < 8; ++k) {
      float a = __expf(e[k] - mn);
      s += a;
      const __half2* hp = (const __half2*)&xv[k];
      float2 f0 = __half22float2(hp[0]);
      float2 f1 = __half22float2(hp[1]);
      float2 f2 = __half22float2(hp[2]);
      float2 f3 = __half22float2(hp[3]);
      o[0] += a * f0.x; o[1] += a * f0.y;
      o[2] += a * f1.x; o[3] += a * f1.y;
      o[4] += a * f2.x; o[5] += a * f2.y;
      o[6] += a * f3.x; o[7] += a * f3.y;
    }
    m = mn;
  }

  const float sc = fw / s;
#pragma unroll
  for (int c = 0; c < 8; ++c) {
    float t = o[c] * sc;
    t += __shfl_xor(t, 16);
    t += __shfl_xor(t, 32);
    o[c] = t;
  }
  if (l < 16) {
    float* wp = wgt4 + (size_t)qid * 128 + l * 8;
    *(float4*)(wp)     = make_float4(o[0], o[1], o[2], o[3]);
    *(float4*)(wp + 4) = make_float4(o[4], o[5], o[6], o[7]);
  }
}

// ---------------------------------------------------------------------------
// finalize: out[n,0:128]=last[n]; out[n,128:256]=sum_f wgt4[f][n]
// ---------------------------------------------------------------------------
__global__ __launch_bounds__(256)
void finalize2(const float* __restrict__ last, const float* __restrict__ wgt4,
               float* __restrict__ out)
{
  int idx = blockIdx.x * 256 + threadIdx.x;
  int n = idx >> 6, q = idx & 63;
  float4 v;
  if (q < 32) {
    v = *(const float4*)(last + (size_t)n * 128 + 4 * q);
  } else {
    int c = (q - 32) * 4;
    v = make_float4(0.f, 0.f, 0.f, 0.f);
#pragma unroll
    for (int f = 0; f < 4; ++f) {
      float4 t = *(const float4*)(wgt4 + ((size_t)f * 16384 + n) * 128 + c);
      v.x += t.x; v.y += t.y; v.z += t.z; v.w += t.w;
    }
  }
  *(float4*)(out + (size_t)n * 256 + 4 * q) = v;
}

extern "C" void kernel_launch(void* const* d_in, const int* in_sizes, int n_in,
                              void* d_out, int out_size, void* d_ws, size_t ws_size,
                              hipStream_t stream)
{
  (void)in_sizes; (void)n_in; (void)out_size; (void)ws_size;
  const float* seq = (const float*)d_in[0];
  const float* W1  = (const float*)d_in[1];
  const float* b1  = (const float*)d_in[2];
  const float* W2  = (const float*)d_in[3];
  const float* b2  = (const float*)d_in[4];
  const float* Wl  = (const float*)d_in[5];
  const float* Wr  = (const float*)d_in[6];
  const float* aw  = (const float*)d_in[7];
  float* out = (float*)d_out;

  // workspace layout (float offsets); ~178 MiB total
  float* ws = (float*)d_ws;
  float* S             = ws;                                   // 16,777,216 f (dist phase)
  __half* xrh          = (__half*)ws;                          // alias: 65536x512 half (after dist)
  unsigned short* seqbf = (unsigned short*)(ws + 16777216);    // 10,485,760 us
  unsigned short* h1bf  = (unsigned short*)(ws + 22020096);    // 10,485,760 us
  __half* xlh           = (__half*)(ws + 22020096);            // alias after mlp2: 16384x512 half
  unsigned short* ylay  = (unsigned short*)(ws + 27262976);    // 6,291,456 us
  unsigned short* xlay  = (unsigned short*)(ws + 30408704);    // 25,165,824 us
  float* wgt4           = ws + 30408704;                       // alias after xr gemm: 8,388,608 f
  float* gfea           = ws + 42991616;                       // 20,480
  float* attn           = gfea + 20480;                        // 16
  float* xsq            = attn + 16;                           // 65,536
  int*   nbr            = (int*)(xsq + 65536);                 // 1,048,576 ints
  unsigned short* W1t   = (unsigned short*)(nbr + 1048576);    // 16,384 us
  unsigned short* W2t   = W1t + 16384;                         // 131,072 us
  unsigned short* Wlv   = W2t + 131072;                        // 196,608 us
  unsigned short* Wrv   = Wlv + 196608;                        // 196,608 us
  __half* awh           = (__half*)(Wrv + 196608);             // 512 halves

  (void)hipMemsetAsync(gfea, 0, 20480 * sizeof(float), stream);

  // conversions
  convert_inputs<<<10240, 256, 0, stream>>>(seq, seqbf, ylay, xlay, xsq);
  convert_weights<<<2114, 256, 0, stream>>>(W1, W2, Wl, Wr, aw, W1t, W2t, Wlv, Wrv, awh);

  // MLP (bf16 MFMA) + temporal attention
  nt_mfma<1><<<dim3(1, 640), 256, 0, stream>>>(seqbf, W1t, b1, h1bf, 128, 128);
  nt_mfma<2><<<dim3(8, 640), 256, 0, stream>>>(h1bf, W2t, b2, gfea, 128, 0);
  temporal_attn<<<1, 1024, 0, stream>>>(gfea, attn);

  // KNN: 16x (split-bf16 dist MFMA + topk)
  for (int f = 0; f < 4; ++f)
    for (int b = 0; b < 4; ++b) {
      nt_mfma<0><<<dim3(32, 32), 256, 0, stream>>>(
          ylay + (size_t)b * 4096 * 384,
          xlay + ((size_t)f * 16384 + (size_t)b * 4096) * 384,
          xsq + f * 16384 + b * 4096, S, 384, 4096);
      topk2<<<1024, 256, 0, stream>>>(S, nbr + (f * 16384 + b * 4096) * 16, b * 4096);
    }

  // GAT projections (split-bf16 MFMA -> half) — xrh aliases S (dist done)
  nt_mfma<3><<<dim3(4, 128), 256, 0, stream>>>(ylay, Wlv, nullptr, xlh, 384, 512);
  nt_mfma<3><<<dim3(4, 512), 256, 0, stream>>>(xlay, Wrv, nullptr, xrh, 384, 512);

  // GAT gather/softmax/aggregate, all 4 frames, chunked single fetch
  gat6<<<16384, 256, 0, stream>>>(xlh, xrh, nbr, awh, attn, wgt4);

  finalize2<<<4096, 256, 0, stream>>>(seq + (size_t)4 * 16384 * 128, wgt4, out);
}

// Round 8
// 853.094 us; speedup vs baseline: 1.5073x; 1.1972x over previous
//
#include <hip/hip_runtime.h>
#include <hip/hip_bf16.h>
#include <hip/hip_fp16.h>

// T=5, B=4, M=4096, N=16384, C=128, G=1024, H=4, K=16. fp32 in/out.

typedef __bf16 v8bf __attribute__((ext_vector_type(8)));
typedef float  v4f  __attribute__((ext_vector_type(4)));

__device__ __forceinline__ float lrelu(float x) { return fmaxf(x, 0.2f * x); }

__device__ __forceinline__ unsigned short f2bf(float x) {
  __hip_bfloat16 h = __float2bfloat16(x);
  return __builtin_bit_cast(unsigned short, h);
}
__device__ __forceinline__ float bf2f(unsigned short u) {
  unsigned int t = ((unsigned int)u) << 16;
  return __builtin_bit_cast(float, t);
}

#define GLOAD_LDS16(gp, lp)                                                   \
  __builtin_amdgcn_global_load_lds(                                           \
      (const __attribute__((address_space(1))) void*)(gp),                    \
      (__attribute__((address_space(3))) void*)(lp), 16, 0, 0)

// ---------------------------------------------------------------------------
// Unified NT bf16 MFMA GEMM (MLP + projections).
// EP 1: mlp1:  out bf16 = lrelu(acc + aux[col]); ldc
// EP 2: mlp2:  column mean over 128-row tile of lrelu(acc+aux[col]) ->
//              atomicAdd(outv + (m0>>12)*1024 + col)
// EP 3: xl/xr: out half = acc; ldc
// ---------------------------------------------------------------------------
template<int EP>
__global__ __launch_bounds__(256, 2)
void nt_mfma(const unsigned short* __restrict__ A, const unsigned short* __restrict__ B,
             const float* __restrict__ aux, void* __restrict__ outv, int K, int ldc)
{
  __shared__ __align__(16) unsigned short smem[8192];
  unsigned short* As = smem;
  unsigned short* Bs = smem + 4096;
  const int tid = threadIdx.x;
  const int l = tid & 63;
  const int w = tid >> 6;
  const int wm = w & 1, wn = w >> 1;
  const int m0 = blockIdx.y << 7, n0 = blockIdx.x << 7;
  const int fr = l & 15, quad = l >> 4;
  const int kt = K >> 5;

  const int r0 = tid >> 2, s0 = tid & 3;
  const unsigned short* Aa = A + (size_t)(m0 + r0) * K + s0 * 8;
  const unsigned short* Ab = A + (size_t)(m0 + r0 + 64) * K + s0 * 8;
  const unsigned short* Ba = B + (size_t)(n0 + r0) * K + s0 * 8;
  const unsigned short* Bb = B + (size_t)(n0 + r0 + 64) * K + s0 * 8;
  unsigned short* Ap0 = As + tid * 8;
  unsigned short* Ap1 = As + (tid + 256) * 8;
  unsigned short* Bp0 = Bs + tid * 8;
  unsigned short* Bp1 = Bs + (tid + 256) * 8;

  v4f acc[4][4];
#pragma unroll
  for (int i = 0; i < 4; ++i)
#pragma unroll
    for (int j = 0; j < 4; ++j) acc[i][j] = (v4f){0.f, 0.f, 0.f, 0.f};

  for (int ks = 0; ks < kt; ++ks) {
    GLOAD_LDS16(Aa + ks * 32, Ap0);
    GLOAD_LDS16(Ab + ks * 32, Ap1);
    GLOAD_LDS16(Ba + ks * 32, Bp0);
    GLOAD_LDS16(Bb + ks * 32, Bp1);
    __syncthreads();
    v8bf af[4], bf[4];
#pragma unroll
    for (int i = 0; i < 4; ++i)
      af[i] = *(const v8bf*)(As + (wm * 64 + i * 16 + fr) * 32 + quad * 8);
#pragma unroll
    for (int j = 0; j < 4; ++j)
      bf[j] = *(const v8bf*)(Bs + (wn * 64 + j * 16 + fr) * 32 + quad * 8);
#pragma unroll
    for (int i = 0; i < 4; ++i)
#pragma unroll
      for (int j = 0; j < 4; ++j)
        acc[i][j] = __builtin_amdgcn_mfma_f32_16x16x32_bf16(af[i], bf[j], acc[i][j], 0, 0, 0);
    __syncthreads();
  }

  if (EP == 1) {
    unsigned short* O = (unsigned short*)outv;
#pragma unroll
    for (int j = 0; j < 4; ++j) {
      int col = n0 + wn * 64 + j * 16 + fr;
      float bias = aux[col];
#pragma unroll
      for (int i = 0; i < 4; ++i) {
        int row = m0 + wm * 64 + i * 16 + quad * 4;
#pragma unroll
        for (int r = 0; r < 4; ++r)
          O[(size_t)(row + r) * ldc + col] = f2bf(lrelu(acc[i][j][r] + bias));
      }
    }
  } else if (EP == 2) {
    __syncthreads();
    float* red = (float*)smem;
#pragma unroll
    for (int j = 0; j < 4; ++j) {
      int lcol = wn * 64 + j * 16 + fr;
      float bias = aux[n0 + lcol];
      float s = 0.f;
#pragma unroll
      for (int i = 0; i < 4; ++i)
#pragma unroll
        for (int r = 0; r < 4; ++r) s += lrelu(acc[i][j][r] + bias);
      s += __shfl_xor(s, 16);
      s += __shfl_xor(s, 32);
      if (quad == 0) red[w * 128 + lcol] = s;
    }
    __syncthreads();
    if (tid < 128) {
      float s = (tid < 64) ? red[0 * 128 + tid] + red[1 * 128 + tid]
                           : red[2 * 128 + tid] + red[3 * 128 + tid];
      atomicAdd((float*)outv + ((m0 >> 12) << 10) + n0 + tid, s * (1.0f / 4096.0f));
    }
  } else {  // EP == 3: half store
    __half* O = (__half*)outv;
#pragma unroll
    for (int j = 0; j < 4; ++j) {
      int col = n0 + wn * 64 + j * 16 + fr;
#pragma unroll
      for (int i = 0; i < 4; ++i) {
        int row = m0 + wm * 64 + i * 16 + quad * 4;
#pragma unroll
        for (int r = 0; r < 4; ++r)
          O[(size_t)(row + r) * ldc + col] = __float2half(acc[i][j][r]);
      }
    }
  }
}

// ---------------------------------------------------------------------------
// knn_fused: dist GEMM + exact per-row top-16, S never materialized.
// Grid 512 = 16 (f,b) pairs x 32 row-blocks of 128. Per col-tile (32 of 128
// cols): m97-style MFMA K-loop (K=384 split-bf16), then threshold selection:
// value v=2*acc-xsq[col] is a candidate iff v > tau[row] (tau = min of row's
// current top-16). Candidates pushed to a 24/row LDS buffer via LDS atomics;
// owner thread (tid<128, one per row) merges into a register-held top-16.
// `pushed` bitmask + block-wide retry loop make overflow exact: each retry
// marks >=24 new values per overflowing row -> <=6 iterations.
// ---------------------------------------------------------------------------
__global__ __launch_bounds__(256, 2)
void knn_fused(const unsigned short* __restrict__ ylay,
               const unsigned short* __restrict__ xlay,
               const float* __restrict__ xsq, int* __restrict__ nbrOut)
{
  __shared__ __align__(16) unsigned short As[4096];
  __shared__ __align__(16) unsigned short Bs[4096];
  __shared__ float candV[128 * 24];
  __shared__ int   candI[128 * 24];
  __shared__ float tauS[128];
  __shared__ int   cntS[128];
  __shared__ int   flagS;

  const int tid = threadIdx.x;
  const int l = tid & 63;
  const int w = tid >> 6;
  const int wm = w & 1, wn = w >> 1;
  const int pair = blockIdx.x >> 5;
  const int rb = blockIdx.x & 31;
  const int f = pair >> 2, b = pair & 3;
  const int m0 = rb << 7;
  const int fr = l & 15, quad = l >> 4;

  const unsigned short* A = ylay + (size_t)b * 4096 * 384;
  const unsigned short* B = xlay + ((size_t)f * 16384 + (size_t)b * 4096) * 384;
  const float* xq = xsq + f * 16384 + b * 4096;

  const int r0 = tid >> 2, s0 = tid & 3;
  const unsigned short* Aa = A + (size_t)(m0 + r0) * 384 + s0 * 8;
  const unsigned short* Ab = A + (size_t)(m0 + r0 + 64) * 384 + s0 * 8;
  unsigned short* Ap0 = As + tid * 8;
  unsigned short* Ap1 = As + (tid + 256) * 8;
  unsigned short* Bp0 = Bs + tid * 8;
  unsigned short* Bp1 = Bs + (tid + 256) * 8;

  // owner-thread (tid<128) register top-16 for local row = tid
  float tv[16];
  int   ti[16];
#pragma unroll
  for (int k = 0; k < 16; ++k) { tv[k] = -3.0e38f; ti[k] = k; }
  float ownMin = -3.0e38f;
  int ownMinPos = 0;
  if (tid < 128) { tauS[tid] = -3.0e38f; cntS[tid] = 0; }
  if (tid == 0) flagS = 0;

  // lane tau cache for its 16 rows (i,r)
  float tc[16];
#pragma unroll
  for (int i = 0; i < 16; ++i) tc[i] = -3.0e38f;
  __syncthreads();

  for (int ct = 0; ct < 32; ++ct) {
    const int n0 = ct << 7;
    const unsigned short* Ba = B + (size_t)(n0 + r0) * 384 + s0 * 8;
    const unsigned short* Bb = B + (size_t)(n0 + r0 + 64) * 384 + s0 * 8;

    v4f acc[4][4];
#pragma unroll
    for (int i = 0; i < 4; ++i)
#pragma unroll
      for (int j = 0; j < 4; ++j) acc[i][j] = (v4f){0.f, 0.f, 0.f, 0.f};

    for (int ks = 0; ks < 12; ++ks) {
      GLOAD_LDS16(Aa + ks * 32, Ap0);
      GLOAD_LDS16(Ab + ks * 32, Ap1);
      GLOAD_LDS16(Ba + ks * 32, Bp0);
      GLOAD_LDS16(Bb + ks * 32, Bp1);
      __syncthreads();
      v8bf af[4], bf[4];
#pragma unroll
      for (int i = 0; i < 4; ++i)
        af[i] = *(const v8bf*)(As + (wm * 64 + i * 16 + fr) * 32 + quad * 8);
#pragma unroll
      for (int j = 0; j < 4; ++j)
        bf[j] = *(const v8bf*)(Bs + (wn * 64 + j * 16 + fr) * 32 + quad * 8);
#pragma unroll
      for (int i = 0; i < 4; ++i)
#pragma unroll
        for (int j = 0; j < 4; ++j)
          acc[i][j] = __builtin_amdgcn_mfma_f32_16x16x32_bf16(af[i], bf[j], acc[i][j], 0, 0, 0);
      __syncthreads();
    }

    float xs[4];
#pragma unroll
    for (int j = 0; j < 4; ++j) xs[j] = xq[n0 + wn * 64 + j * 16 + fr];

    unsigned long long pushed = 0ull;
    for (;;) {
      // scan: rare candidates -> LDS buffer
#pragma unroll
      for (int i = 0; i < 4; ++i)
#pragma unroll
        for (int r = 0; r < 4; ++r) {
          const int lrow = wm * 64 + i * 16 + quad * 4 + r;
          const float tau = tc[i * 4 + r];
#pragma unroll
          for (int j = 0; j < 4; ++j) {
            const int bit = i * 16 + j * 4 + r;
            float v = 2.f * acc[i][j][r] - xs[j];
            if (v > tau && !((pushed >> bit) & 1ull)) {
              int pos = atomicAdd(&cntS[lrow], 1);
              if (pos < 24) {
                candV[lrow * 24 + pos] = v;
                candI[lrow * 24 + pos] = n0 + wn * 64 + j * 16 + fr;
                pushed |= (1ull << bit);
              }
            }
          }
        }
      __syncthreads();
      // owner merge
      if (tid < 128) {
        int c = cntS[tid];
        int cc = c < 24 ? c : 24;
        for (int q = 0; q < cc; ++q) {
          float v = candV[tid * 24 + q];
          if (v > ownMin) {
            tv[ownMinPos] = v;
            ti[ownMinPos] = candI[tid * 24 + q];
            ownMin = tv[0]; ownMinPos = 0;
#pragma unroll
            for (int k = 1; k < 16; ++k)
              if (tv[k] < ownMin) { ownMin = tv[k]; ownMinPos = k; }
          }
        }
        tauS[tid] = ownMin;
        if (c > 24) flagS = 1;
        cntS[tid] = 0;
      }
      __syncthreads();
#pragma unroll
      for (int i = 0; i < 4; ++i)
#pragma unroll
        for (int r = 0; r < 4; ++r)
          tc[i * 4 + r] = tauS[wm * 64 + i * 16 + quad * 4 + r];
      int ov = flagS;
      __syncthreads();
      if (tid == 0) flagS = 0;
      if (!ov) break;
    }
  }

  if (tid < 128) {
    const int base = b * 4096;
    int* outp = nbrOut + ((size_t)(f * 16384 + b * 4096) + m0 + tid) * 16;
#pragma unroll
    for (int k = 0; k < 16; ++k) outp[k] = base + ti[k];
  }
}

// ---------------------------------------------------------------------------
// convert_inputs (unchanged)
// ---------------------------------------------------------------------------
__global__ __launch_bounds__(256)
void convert_inputs(const float* __restrict__ seq, unsigned short* __restrict__ seqbf,
                    unsigned short* __restrict__ ylay, unsigned short* __restrict__ xlay,
                    float* __restrict__ xsq)
{
  const int tid = threadIdx.x;
  const int row = blockIdx.x * 8 + (tid >> 5);
  const int c4 = tid & 31;
  float4 v = *(const float4*)(seq + (size_t)row * 128 + c4 * 4);
  ushort4 hi, lo;
  hi.x = f2bf(v.x); lo.x = f2bf(v.x - bf2f(hi.x));
  hi.y = f2bf(v.y); lo.y = f2bf(v.y - bf2f(hi.y));
  hi.z = f2bf(v.z); lo.z = f2bf(v.z - bf2f(hi.z));
  hi.w = f2bf(v.w); lo.w = f2bf(v.w - bf2f(hi.w));
  *(ushort4*)(seqbf + (size_t)row * 128 + c4 * 4) = hi;
  float ss = v.x * v.x + v.y * v.y + v.z * v.z + v.w * v.w;
#pragma unroll
  for (int off = 16; off; off >>= 1) ss += __shfl_xor(ss, off);
  if (row < 65536) {
    unsigned short* p = xlay + (size_t)row * 384 + c4 * 4;
    *(ushort4*)(p) = hi; *(ushort4*)(p + 128) = lo; *(ushort4*)(p + 256) = hi;
    if (c4 == 0) xsq[row] = ss;
  } else {
    unsigned short* p = ylay + (size_t)(row - 65536) * 384 + c4 * 4;
    *(ushort4*)(p) = hi; *(ushort4*)(p + 128) = hi; *(ushort4*)(p + 256) = lo;
  }
}

// ---------------------------------------------------------------------------
// convert_weights (unchanged)
// ---------------------------------------------------------------------------
__global__ __launch_bounds__(256)
void convert_weights(const float* __restrict__ W1, const float* __restrict__ W2,
                     const float* __restrict__ Wl, const float* __restrict__ Wr,
                     const float* __restrict__ aw,
                     unsigned short* __restrict__ W1t, unsigned short* __restrict__ W2t,
                     unsigned short* __restrict__ Wlv, unsigned short* __restrict__ Wrv,
                     __half* __restrict__ awh)
{
  int idx = blockIdx.x * 256 + threadIdx.x;
  if (idx < 16384) {
    int n = idx >> 7, k = idx & 127;
    W1t[idx] = f2bf(W1[k * 128 + n]);
  } else if (idx < 147456) {
    int i = idx - 16384; int n = i >> 7, k = i & 127;
    W2t[i] = f2bf(W2[k * 1024 + n]);
  } else if (idx < 344064) {
    int i = idx - 147456; int n = i / 384, k = i % 384;
    int s = k >> 7, kk = k & 127;
    float wv = Wl[kk * 512 + n];
    unsigned short h = f2bf(wv);
    Wlv[i] = (s == 1) ? f2bf(wv - bf2f(h)) : h;
  } else if (idx < 540672) {
    int i = idx - 344064; int n = i / 384, k = i % 384;
    int s = k >> 7, kk = k & 127;
    float wv = Wr[kk * 512 + n];
    unsigned short h = f2bf(wv);
    Wrv[i] = (s == 2) ? f2bf(wv - bf2f(h)) : h;
  } else if (idx < 541184) {
    int i = idx - 540672;
    awh[i] = __float2half(aw[i]);
  }
}

// ---------------------------------------------------------------------------
// Temporal attention weights (unchanged)
// ---------------------------------------------------------------------------
__global__ __launch_bounds__(1024)
void temporal_attn(const float* __restrict__ gfea, float* __restrict__ attnw)
{
  const int tid = threadIdx.x;
  const int w = tid >> 6, l = tid & 63;
  const int b = w >> 2, i = w & 3;
  const float* q  = gfea + (16 + b) * 1024;
  const float* kv = gfea + (i * 4 + b) * 1024;
  float p = 0.f;
  for (int g = l; g < 1024; g += 64) p += q[g] * kv[g];
#pragma unroll
  for (int off = 32; off; off >>= 1) p += __shfl_xor(p, off);
  __shared__ float sc[16];
  if (l == 0) sc[w] = p * 0.03125f;
  __syncthreads();
  if (tid < 4) {
    float v0 = sc[tid * 4 + 0], v1 = sc[tid * 4 + 1];
    float v2 = sc[tid * 4 + 2], v3 = sc[tid * 4 + 3];
    float mm = fmaxf(fmaxf(v0, v1), fmaxf(v2, v3));
    v0 = __expf(v0 - mm); v1 = __expf(v1 - mm);
    v2 = __expf(v2 - mm); v3 = __expf(v3 - mm);
    float inv = 1.f / (v0 + v1 + v2 + v3);
    attnw[tid * 4 + 0] = v0 * inv;
    attnw[tid * 4 + 1] = v1 * inv;
    attnw[tid * 4 + 2] = v2 * inv;
    attnw[tid * 4 + 3] = v3 * inv;
  }
}

// ---------------------------------------------------------------------------
// gat6 (chunked single-fetch) + XCD-aware swizzle: blockIdx%8 ~ XCD -> batch b,
// so each XCD's xlh gather working set is one 4 MB slice (L2-resident).
// ---------------------------------------------------------------------------
__global__ __launch_bounds__(256)
void gat6(const __half* __restrict__ xlh, const __half* __restrict__ xrh,
          const int* __restrict__ nbr, const __half* __restrict__ awh,
          const float* __restrict__ attnw, float* __restrict__ wgt4)
{
  const int tid = threadIdx.x;
  const int l = tid & 63;
  const int blk = blockIdx.x;
  const int r8 = blk & 7;
  const int b = r8 >> 1;                      // XCD pair -> batch
  const int g = ((blk >> 3) << 1) | (r8 & 1); // [0, 4096)
  const int f = g >> 10;
  const int n4 = g & 1023;
  const int qid = f * 16384 + b * 4096 + n4 * 4 + (tid >> 6);
  const int h = l >> 4, cp = l & 15;
  const float fw = attnw[b * 4 + f] * 0.25f;

  const int jl = nbr[qid * 16 + (l & 15)];
  const __half* xbase = xlh + h * 128 + cp * 8;

  const __half2* xrp = (const __half2*)(xrh + (size_t)qid * 512 + h * 128 + cp * 8);
  float2 xr0 = __half22float2(xrp[0]), xr1 = __half22float2(xrp[1]);
  float2 xr2 = __half22float2(xrp[2]), xr3 = __half22float2(xrp[3]);
  const __half2* awp = (const __half2*)(awh + h * 128 + cp * 8);
  float2 aw0 = __half22float2(awp[0]), aw1 = __half22float2(awp[1]);
  float2 aw2 = __half22float2(awp[2]), aw3 = __half22float2(awp[3]);

  float m = -3.0e38f, s = 0.f;
  float o[8];
#pragma unroll
  for (int c = 0; c < 8; ++c) o[c] = 0.f;

  for (int ch = 0; ch < 2; ++ch) {
    float4 xv[8];
#pragma unroll
    for (int k = 0; k < 8; ++k) {
      int j = __shfl(jl, ch * 8 + k);
      xv[k] = *(const float4*)(xbase + (size_t)j * 512);
    }
    float e[8];
#pragma unroll
    for (int k = 0; k < 8; ++k) {
      const __half2* hp = (const __half2*)&xv[k];
      float2 x0 = __half22float2(hp[0]), x1 = __half22float2(hp[1]);
      float2 x2 = __half22float2(hp[2]), x3 = __half22float2(hp[3]);
      float p = 0.f;
      p += lrelu(x0.x + xr0.x) * aw0.x + lrelu(x0.y + xr0.y) * aw0.y;
      p += lrelu(x1.x + xr1.x) * aw1.x + lrelu(x1.y + xr1.y) * aw1.y;
      p += lrelu(x2.x + xr2.x) * aw2.x + lrelu(x2.y + xr2.y) * aw2.y;
      p += lrelu(x3.x + xr3.x) * aw3.x + lrelu(x3.y + xr3.y) * aw3.y;
      p += __shfl_xor(p, 1);
      p += __shfl_xor(p, 2);
      p += __shfl_xor(p, 4);
      p += __shfl_xor(p, 8);
      e[k] = p;
    }
    float mc = e[0];
#pragma unroll
    for (int k = 1; k < 8; ++k) mc = fmaxf(mc, e[k]);
    float mn = fmaxf(m, mc);
    float cr = __expf(m - mn);
    s *= cr;
#pragma unroll
    for (int c = 0; c < 8; ++c) o[c] *= cr;
#pragma unroll
    for (int k = 0; k < 8; ++k) {
      float a = __expf(e[k] - mn);
      s += a;
      const __half2* hp = (const __half2*)&xv[k];
      float2 f0 = __half22float2(hp[0]);
      float2 f1 = __half22float2(hp[1]);
      float2 f2 = __half22float2(hp[2]);
      float2 f3 = __half22float2(hp[3]);
      o[0] += a * f0.x; o[1] += a * f0.y;
      o[2] += a * f1.x; o[3] += a * f1.y;
      o[4] += a * f2.x; o[5] += a * f2.y;
      o[6] += a * f3.x; o[7] += a * f3.y;
    }
    m = mn;
  }

  const float sc = fw / s;
#pragma unroll
  for (int c = 0; c < 8; ++c) {
    float t = o[c] * sc;
    t += __shfl_xor(t, 16);
    t += __shfl_xor(t, 32);
    o[c] = t;
  }
  if (l < 16) {
    float* wp = wgt4 + (size_t)qid * 128 + l * 8;
    *(float4*)(wp)     = make_float4(o[0], o[1], o[2], o[3]);
    *(float4*)(wp + 4) = make_float4(o[4], o[5], o[6], o[7]);
  }
}

// ---------------------------------------------------------------------------
// finalize (unchanged)
// ---------------------------------------------------------------------------
__global__ __launch_bounds__(256)
void finalize2(const float* __restrict__ last, const float* __restrict__ wgt4,
               float* __restrict__ out)
{
  int idx = blockIdx.x * 256 + threadIdx.x;
  int n = idx >> 6, q = idx & 63;
  float4 v;
  if (q < 32) {
    v = *(const float4*)(last + (size_t)n * 128 + 4 * q);
  } else {
    int c = (q - 32) * 4;
    v = make_float4(0.f, 0.f, 0.f, 0.f);
#pragma unroll
    for (int f = 0; f < 4; ++f) {
      float4 t = *(const float4*)(wgt4 + ((size_t)f * 16384 + n) * 128 + c);
      v.x += t.x; v.y += t.y; v.z += t.z; v.w += t.w;
    }
  }
  *(float4*)(out + (size_t)n * 256 + 4 * q) = v;
}

extern "C" void kernel_launch(void* const* d_in, const int* in_sizes, int n_in,
                              void* d_out, int out_size, void* d_ws, size_t ws_size,
                              hipStream_t stream)
{
  (void)in_sizes; (void)n_in; (void)out_size; (void)ws_size;
  const float* seq = (const float*)d_in[0];
  const float* W1  = (const float*)d_in[1];
  const float* b1  = (const float*)d_in[2];
  const float* W2  = (const float*)d_in[3];
  const float* b2  = (const float*)d_in[4];
  const float* Wl  = (const float*)d_in[5];
  const float* Wr  = (const float*)d_in[6];
  const float* aw  = (const float*)d_in[7];
  float* out = (float*)d_out;

  // workspace layout (float offsets); ~178 MiB total
  float* ws = (float*)d_ws;
  __half* xrh          = (__half*)ws;                          // 65536x512 half (32 MB region)
  unsigned short* seqbf = (unsigned short*)(ws + 16777216);    // 10,485,760 us
  unsigned short* h1bf  = (unsigned short*)(ws + 22020096);    // 10,485,760 us
  __half* xlh           = (__half*)(ws + 22020096);            // alias after mlp2: 16384x512 half
  unsigned short* ylay  = (unsigned short*)(ws + 27262976);    // 6,291,456 us
  unsigned short* xlay  = (unsigned short*)(ws + 30408704);    // 25,165,824 us
  float* wgt4           = ws + 30408704;                       // alias after xr gemm: 8,388,608 f
  float* gfea           = ws + 42991616;                       // 20,480
  float* attn           = gfea + 20480;                        // 16
  float* xsq            = attn + 16;                           // 65,536
  int*   nbr            = (int*)(xsq + 65536);                 // 1,048,576 ints
  unsigned short* W1t   = (unsigned short*)(nbr + 1048576);    // 16,384 us
  unsigned short* W2t   = W1t + 16384;                         // 131,072 us
  unsigned short* Wlv   = W2t + 131072;                        // 196,608 us
  unsigned short* Wrv   = Wlv + 196608;                        // 196,608 us
  __half* awh           = (__half*)(Wrv + 196608);             // 512 halves

  (void)hipMemsetAsync(gfea, 0, 20480 * sizeof(float), stream);

  // conversions
  convert_inputs<<<10240, 256, 0, stream>>>(seq, seqbf, ylay, xlay, xsq);
  convert_weights<<<2114, 256, 0, stream>>>(W1, W2, Wl, Wr, aw, W1t, W2t, Wlv, Wrv, awh);

  // MLP (bf16 MFMA) + temporal attention
  nt_mfma<1><<<dim3(1, 640), 256, 0, stream>>>(seqbf, W1t, b1, h1bf, 128, 128);
  nt_mfma<2><<<dim3(8, 640), 256, 0, stream>>>(h1bf, W2t, b2, gfea, 128, 0);
  temporal_attn<<<1, 1024, 0, stream>>>(gfea, attn);

  // KNN: all 16 pairs fused (dist MFMA + exact top-16), no S buffer
  knn_fused<<<512, 256, 0, stream>>>(ylay, xlay, xsq, nbr);

  // GAT projections (split-bf16 MFMA -> half)
  nt_mfma<3><<<dim3(4, 128), 256, 0, stream>>>(ylay, Wlv, nullptr, xlh, 384, 512);
  nt_mfma<3><<<dim3(4, 512), 256, 0, stream>>>(xlay, Wrv, nullptr, xrh, 384, 512);

  // GAT gather/softmax/aggregate (XCD-swizzled)
  gat6<<<16384, 256, 0, stream>>>(xlh, xrh, nbr, awh, attn, wgt4);

  finalize2<<<4096, 256, 0, stream>>>(seq + (size_t)4 * 16384 * 128, wgt4, out);
}